// Round 2
// baseline (206.773 us; speedup 1.0000x reference)
//
#include <hip/hip_runtime.h>
#include <math.h>

// Problem constants: N=128 features, H=256 hidden, B=16 batch.
//
// Analytic collapse of the reference:
//   S = W1^T W1  [256x256] (symmetric), Q = W2 W2^T [256x256] (symmetric)
//   per sample: d = 1-tanh^2(h), c = -2 z d,  P = S diag(d) W2  [256x128]
//   ||dG||_F^2 = 2 sum_{m,m'} c_m c_m' S[m,m'] ( Q[m,m'] R[m,m'] + M[m,m'] M[m',m] )
//        R = P P^T, M = P W2^T
//   Gamma contraction = 0.5*( W2^T (c .* Pv .* Uv) + P^T (c .* W2v .* Uv) )
//
// Session record (dur_us): R1 145.4 (7 kernels) -> R2 126.9 -> R3 129.0 ->
// R4 218.5 (grid.sync ~35us) -> R5 171.9 -> R6 124.3 -> R7 128.2 ->
// R8 115.0 (3 kernels: fnorm 49KB LDS all-resident + 16 spin-wait epilogue
// blocks, bit-identical) -> R9 (this): ONE kernel, 976 blocks.
//   Deadlock-free by capacity: LDS 37632B <= 40960 (4 blk/CU) via 3-wave
//   reduction scratch + merged Q(32)/W2T(16) blocks; launch_bounds(256,4)
//   caps VGPR at 128 => 1024 resident slots >= 976. Block order is also
//   topological (stage1 -> pmat3 -> producers -> epilogue) as belt+suspenders.
//   Cross-block deps via dual-magic flag pairs (threadfence release +
//   atomicExch; two distinct magics can't match a constant poison fill).
//   SUM/CNT zeroed by prep BEFORE its flag; all users transitively ordered.
//   All compute bodies identical to R8 => bit-identical output expected.
// Lessons: (1) grid.sync ~35us - never. (2) low-occupancy streaming loops
// are latency-bound; LDS staging + 4-wave blocks win. (3) last-arrival
// epilogue fusion loses to dedicated overlap blocks. (4) harness fixed cost
// ~82us (268MB ws re-poison); kernel budget ~33us.

// ws layout (float offsets)
static constexpr int OFF_W2T  = 0;        // [128][256]
static constexpr int OFF_S    = 32768;    // [256][256]
static constexpr int OFF_Q    = 98304;    // [256][256]
static constexpr int OFF_D    = 163840;   // [16][256]
static constexpr int OFF_C    = 167936;   // [16][256]
static constexpr int OFF_UV   = 172032;   // [16][256]
static constexpr int OFF_AV   = 176128;   // [16][256]
static constexpr int OFF_VN   = 180224;   // [16]
static constexpr int OFF_SUM  = 180240;   // [16] float accumulator (fnorm^2/2)
static constexpr int OFF_CNT  = 180256;   // [16] int32 producer-done counters
// flag pairs (int indices into (int*)ws); {MAG1,MAG2} when set
static constexpr int IFL_S    = 180272;        // 64 pairs (S tiles)
static constexpr int IFL_Q    = IFL_S + 128;   // 32 pairs (merged Q blocks)
static constexpr int IFL_T    = IFL_Q + 64;    // 16 pairs (merged W2T blocks)
static constexpr int IFL_PREP = IFL_T + 32;    // 16 pairs (per-sample prep)
static constexpr int IFL_P    = IFL_PREP + 32; // 256 pairs (pmat3 blocks)
static constexpr int OFF_PT   = IFL_P + 512;   // = 181040, [16][128][256]
static constexpr int OFF_PN   = OFF_PT + 16 * 32768;  // [16][256][128]
// total ~= 1.23M floats ~= 4.9 MB

#define MAG1 0x1357ACE5
#define MAG2 0x2468BD1B

__device__ __forceinline__ void set_flag2(int* f) {
    atomicExch(f, MAG1);
    atomicExch(f + 1, MAG2);
}
__device__ __forceinline__ void wait_flag2(int* f) {
    while (atomicAdd(f, 0) != MAG1) __builtin_amdgcn_s_sleep(8);
    while (atomicAdd(f + 1, 0) != MAG2) __builtin_amdgcn_s_sleep(8);
}

// =====================================================================
// Single fused kernel, grid 976 x 256 thr, all-resident at 4 blocks/CU.
//   blk   0.. 63 : S tiles (W1^T W1)
//   blk  64.. 95 : Q (W2 W2^T), 2 tiles each
//   blk  96..111 : W2T transpose, 2 tiles each
//   blk 112..127 : per-sample prep (zeroes SUM/CNT, writes out rows 0..15)
//   blk 128..383 : pmat3 (waits S + prep[b])
//   blk 384..959 : fnorm producers (wait pflags[b] + Q + W2T)
//   blk 960..975 : epilogue (waits pflags[b]; CNT[b]==36 for final scale)
// =====================================================================
__global__ __launch_bounds__(256, 4) void k_all(const float* __restrict__ tptr,
                                                const float* __restrict__ state,
                                                const float* __restrict__ x0,
                                                const float* __restrict__ x1,
                                                const float* __restrict__ W1,
                                                const float* __restrict__ b1,
                                                const float* __restrict__ W2,
                                                float* __restrict__ ws,
                                                float* __restrict__ out) {
    __shared__ __align__(16) float lds[9408];   // 37632 B -> 4 blocks/CU
    int blk = blockIdx.x;
    int tid = threadIdx.x;
    int* flg = (int*)ws;
    int* cnt = flg + OFF_CNT;

    if (blk < 64) {
        // ---- S[m,n] = sum_k W1[k,m] W1[k,n], W1 is [128][256] ----
        float* Ai = lds;             // [32][34] : [k][m]
        float* Aj = lds + 1088;
        int m0 = (blk >> 3) * 32, n0 = (blk & 7) * 32;
        int lx = tid & 31, lr = tid >> 5;
        int tx = tid & 15, ty = tid >> 4;
        float a00 = 0, a01 = 0, a10 = 0, a11 = 0;
        for (int kc = 0; kc < 128; kc += 32) {
            #pragma unroll
            for (int i = 0; i < 4; ++i) {
                int k = lr + 8 * i;
                Ai[k * 34 + lx] = W1[(kc + k) * 256 + m0 + lx];
                Aj[k * 34 + lx] = W1[(kc + k) * 256 + n0 + lx];
            }
            __syncthreads();
            #pragma unroll
            for (int k = 0; k < 32; ++k) {
                float2 a = *(const float2*)&Ai[k * 34 + 2 * ty];
                float2 b = *(const float2*)&Aj[k * 34 + 2 * tx];
                a00 += a.x * b.x; a01 += a.x * b.y;
                a10 += a.y * b.x; a11 += a.y * b.y;
            }
            __syncthreads();
        }
        float* S = ws + OFF_S;
        int m = m0 + 2 * ty, n = n0 + 2 * tx;
        S[m * 256 + n]           = a00;
        S[m * 256 + n + 1]       = a01;
        S[(m + 1) * 256 + n]     = a10;
        S[(m + 1) * 256 + n + 1] = a11;
        __syncthreads();
        if (tid == 0) { __threadfence(); set_flag2(flg + IFL_S + 2 * blk); }
    } else if (blk < 96) {
        // ---- Q[m,n] = sum_j W2[m,j] W2[n,j], W2 is [256][128]; 2 tiles ----
        int bqq = blk - 64;
        for (int hh = 0; hh < 2; ++hh) {
            int bq = bqq + 32 * hh;
            float* Xi = lds;         // [32][34] : [j][m]
            float* Xj = lds + 1088;
            int m0 = (bq >> 3) * 32, n0 = (bq & 7) * 32;
            int lx = tid & 31, lr = tid >> 5;
            int tx = tid & 15, ty = tid >> 4;
            float a00 = 0, a01 = 0, a10 = 0, a11 = 0;
            for (int kc = 0; kc < 128; kc += 32) {
                #pragma unroll
                for (int i = 0; i < 4; ++i) {
                    Xi[lx * 34 + lr + 8 * i] = W2[(m0 + lr + 8 * i) * 128 + kc + lx];
                    Xj[lx * 34 + lr + 8 * i] = W2[(n0 + lr + 8 * i) * 128 + kc + lx];
                }
                __syncthreads();
                #pragma unroll
                for (int k = 0; k < 32; ++k) {
                    float2 a = *(const float2*)&Xi[k * 34 + 2 * ty];
                    float2 b = *(const float2*)&Xj[k * 34 + 2 * tx];
                    a00 += a.x * b.x; a01 += a.x * b.y;
                    a10 += a.y * b.x; a11 += a.y * b.y;
                }
                __syncthreads();
            }
            float* Q = ws + OFF_Q;
            int m = m0 + 2 * ty, n = n0 + 2 * tx;
            Q[m * 256 + n]           = a00;
            Q[m * 256 + n + 1]       = a01;
            Q[(m + 1) * 256 + n]     = a10;
            Q[(m + 1) * 256 + n + 1] = a11;
            __syncthreads();
        }
        if (tid == 0) { __threadfence(); set_flag2(flg + IFL_Q + 2 * bqq); }
    } else if (blk < 112) {
        // ---- W2T[c][r] = W2[r][c]; 2 tiles ----
        int bt = blk - 96;
        for (int hh = 0; hh < 2; ++hh) {
            int b2 = bt + 16 * hh;
            float* tile = lds;  // [32][33]
            int c0 = (b2 & 3) * 32, r0 = (b2 >> 2) * 32;
            int tx = tid & 31, ty = tid >> 5;
            #pragma unroll
            for (int i = 0; i < 32; i += 8)
                tile[(ty + i) * 33 + tx] = W2[(r0 + ty + i) * 128 + c0 + tx];
            __syncthreads();
            float* W2T = ws + OFF_W2T;
            #pragma unroll
            for (int i = 0; i < 32; i += 8)
                W2T[(c0 + ty + i) * 256 + r0 + tx] = tile[tx * 33 + ty + i];
            __syncthreads();
        }
        if (tid == 0) { __threadfence(); set_flag2(flg + IFL_T + 2 * bt); }
    } else if (blk < 128) {
        // ---- per-sample prep ----
        int b = blk - 112;
        float* xs  = lds;
        float* vs  = lds + 128;
        float* red = lds + 256;
        float t = tptr[0];
        float w = 4.f * t * (1.f - t);
        if (tid == 0) {
            ws[OFF_SUM + b] = 0.f;
            cnt[b] = 0;
        }
        if (tid < 128) {
            float dev = state[b * 128 + tid];
            float v   = state[(16 + b) * 128 + tid];
            float xv  = x0[b * 128 + tid] + t * (x1[b * 128 + tid] - x0[b * 128 + tid]) + w * dev;
            xs[tid] = xv;
            vs[tid] = v;
            out[b * 128 + tid] = v;   // first-half output = dev_velocity
            red[tid] = v * v;
        }
        __syncthreads();
        for (int s = 64; s > 0; s >>= 1) {
            if (tid < s) red[tid] += red[tid + s];
            __syncthreads();
        }
        if (tid == 0) ws[OFF_VN + b] = sqrtf(red[0]);

        int m = tid;  // 0..255
        float h = b1[m], uvm = 0.f;
        #pragma unroll 8
        for (int k = 0; k < 128; ++k) {
            float wv = W1[k * 256 + m];    // coalesced
            h   += xs[k] * wv;
            uvm += vs[k] * wv;
        }
        float z  = tanhf(h);
        float dd = 1.f - z * z;
        float cc = -2.f * z * dd;
        const float4* w2r = (const float4*)&W2[m * 128];
        const float4* vs4 = (const float4*)vs;
        float avm = 0.f;
        #pragma unroll 8
        for (int j4 = 0; j4 < 32; ++j4) {
            float4 ww = w2r[j4];
            float4 vv = vs4[j4];
            avm += ww.x * vv.x + ww.y * vv.y + ww.z * vv.z + ww.w * vv.w;
        }
        ws[OFF_D  + b * 256 + m] = dd;
        ws[OFF_C  + b * 256 + m] = cc;
        ws[OFF_UV + b * 256 + m] = uvm;
        ws[OFF_AV + b * 256 + m] = avm;
        __syncthreads();
        if (tid == 0) { __threadfence(); set_flag2(flg + IFL_PREP + 2 * b); }
    } else if (blk < 384) {
        // ---- pmat3: P = S diag(d) W2, 32m x 64j tile, 4x2/thread ----
        int q = blk - 128;
        int b = q >> 4, rem = q & 15;
        int mt = rem >> 1, jt = rem & 1;
        if (tid < 64) wait_flag2(flg + IFL_S + 2 * tid);
        else if (tid == 64) wait_flag2(flg + IFL_PREP + 2 * b);
        __syncthreads();
        __threadfence();

        float* ST = lds;             // [32][36] : [n][m-local]
        float* YT = lds + 1152;      // [32][68] : [n][j-local]
        const float* Smat = ws + OFF_S;
        const float* dvec = ws + OFF_D + b * 256;
        int m0 = mt * 32, j0 = jt * 64;
        int n = tid >> 3, c4 = (tid & 7) * 4;    // staging
        int ty = tid >> 5, tx = tid & 31;        // compute: 4m x 2j
        float acc[4][2] = {};
        for (int nc = 0; nc < 256; nc += 32) {
            *(float4*)&ST[n * 36 + c4] = *(const float4*)&Smat[(nc + n) * 256 + m0 + c4];
            float dn = dvec[nc + n];
            #pragma unroll
            for (int i = 0; i < 2; ++i) {
                int col = c4 + 32 * i;
                float4 wv = *(const float4*)&W2[(nc + n) * 128 + j0 + col];
                wv.x *= dn; wv.y *= dn; wv.z *= dn; wv.w *= dn;
                *(float4*)&YT[n * 68 + col] = wv;
            }
            __syncthreads();
            #pragma unroll 8
            for (int k = 0; k < 32; ++k) {
                float4 a  = *(const float4*)&ST[k * 36 + 4 * ty];
                float2 bb = *(const float2*)&YT[k * 68 + 2 * tx];
                acc[0][0] += a.x * bb.x; acc[0][1] += a.x * bb.y;
                acc[1][0] += a.y * bb.x; acc[1][1] += a.y * bb.y;
                acc[2][0] += a.z * bb.x; acc[2][1] += a.z * bb.y;
                acc[3][0] += a.w * bb.x; acc[3][1] += a.w * bb.y;
            }
            __syncthreads();
        }
        float* ptb = ws + OFF_PT + b * 32768;
        float* pnb = ws + OFF_PN + b * 32768;
        #pragma unroll
        for (int jj = 0; jj < 2; ++jj) {
            float4 v = make_float4(acc[0][jj], acc[1][jj], acc[2][jj], acc[3][jj]);
            *(float4*)&ptb[(j0 + 2 * tx + jj) * 256 + m0 + 4 * ty] = v;
        }
        #pragma unroll
        for (int ii = 0; ii < 4; ++ii) {
            float2 v = make_float2(acc[ii][0], acc[ii][1]);
            *(float2*)&pnb[(m0 + 4 * ty + ii) * 128 + j0 + 2 * tx] = v;
        }
        __syncthreads();
        if (tid == 0) { __threadfence(); set_flag2(flg + IFL_P + 2 * q); }
    } else if (blk < 960) {
        // ---- fnorm producer: triangular (mi,mj) tile, 4 waves x j-quarter ----
        int q = blk - 384;
        int idx = q >> 4;          // 0..35 triangular tile
        int b   = q & 15;
        if (tid < 16) wait_flag2(flg + IFL_P + 2 * (16 * b + tid));
        else if (tid < 48) wait_flag2(flg + IFL_Q + 2 * (tid - 16));
        else if (tid < 64) wait_flag2(flg + IFL_T + 2 * (tid - 48));
        __syncthreads();
        __threadfence();

        int tj = 0;
        while ((tj + 1) * (tj + 2) / 2 <= idx) ++tj;
        int ti = idx - tj * (tj + 1) / 2;      // ti <= tj
        int mi0 = ti * 32, mj0 = tj * 32;
        float* PiT = lds;              // [64][32] per round
        float* PjT = lds + 2048;
        float* WiT = lds + 4096;
        float* WjT = lds + 6144;
        const float* ptb  = ws + OFF_PT + b * 32768;
        const float* W2T  = ws + OFF_W2T;
        const float* Smat = ws + OFF_S;
        const float* Qmat = ws + OFF_Q;
        int jr = tid >> 3, jc4 = (tid & 7) * 4;
        int w = tid >> 6, s = tid & 63;
        int ty = s >> 3, tx = s & 7;
        float r[4][4] = {}, f[4][4] = {}, g[4][4] = {};
        // Two staging rounds; round rr stages global j = 32*(l>>4)+16*rr+(l&15)
        // for local row l in [0,64): wave w's rows [16w,16w+16) are global
        // j in [32w+16rr, +16) -> same per-wave j set & order as R8.
        #pragma unroll
        for (int rr = 0; rr < 2; ++rr) {
            #pragma unroll
            for (int it = 0; it < 2; ++it) {
                int l = jr + 32 * it;
                int j = 32 * (l >> 4) + 16 * rr + (l & 15);
                *(float4*)&PiT[l * 32 + jc4] = *(const float4*)&ptb[j * 256 + mi0 + jc4];
                *(float4*)&PjT[l * 32 + jc4] = *(const float4*)&ptb[j * 256 + mj0 + jc4];
                *(float4*)&WiT[l * 32 + jc4] = *(const float4*)&W2T[j * 256 + mi0 + jc4];
                *(float4*)&WjT[l * 32 + jc4] = *(const float4*)&W2T[j * 256 + mj0 + jc4];
            }
            __syncthreads();
            #pragma unroll 4
            for (int jj = 0; jj < 16; ++jj) {
                int l = 16 * w + jj;
                float4 pi4 = *(const float4*)&PiT[l * 32 + 4 * ty];
                float4 pj4 = *(const float4*)&PjT[l * 32 + 4 * tx];
                float4 wi4 = *(const float4*)&WiT[l * 32 + 4 * ty];
                float4 wj4 = *(const float4*)&WjT[l * 32 + 4 * tx];
                float pi[4] = {pi4.x, pi4.y, pi4.z, pi4.w};
                float pj[4] = {pj4.x, pj4.y, pj4.z, pj4.w};
                float wi[4] = {wi4.x, wi4.y, wi4.z, wi4.w};
                float wj[4] = {wj4.x, wj4.y, wj4.z, wj4.w};
                #pragma unroll
                for (int ii = 0; ii < 4; ++ii)
                    #pragma unroll
                    for (int kk = 0; kk < 4; ++kk) {
                        r[ii][kk] += pi[ii] * pj[kk];   // R[mi,mj]
                        f[ii][kk] += pi[ii] * wj[kk];   // M[mi,mj]
                        g[ii][kk] += pj[kk] * wi[ii];   // M[mj,mi]
                    }
            }
            __syncthreads();   // round rr done; safe to restage
        }
        // 3-wave scratch: waves 1..3 spill; wave 0 keeps registers.
        if (w != 0) {
            float* scr = lds;
            int base = ((w - 1) * 64 + s) * 49;   // stride 49: conflict-light
            #pragma unroll
            for (int ii = 0; ii < 4; ++ii)
                #pragma unroll
                for (int kk = 0; kk < 4; ++kk) {
                    scr[base + ii * 4 + kk]      = r[ii][kk];
                    scr[base + 16 + ii * 4 + kk] = f[ii][kk];
                    scr[base + 32 + ii * 4 + kk] = g[ii][kk];
                }
        }
        __syncthreads();
        if (tid < 64) {
            float tr[16], tf[16], tg[16];
            #pragma unroll
            for (int ii = 0; ii < 4; ++ii)
                #pragma unroll
                for (int kk = 0; kk < 4; ++kk) {
                    tr[ii * 4 + kk] = r[ii][kk];
                    tf[ii * 4 + kk] = f[ii][kk];
                    tg[ii * 4 + kk] = g[ii][kk];
                }
            // add waves 1..3 in order -> same w0+w1+w2+w3 order as R8
            for (int ww = 0; ww < 3; ++ww) {
                const float* sc = lds + (ww * 64 + tid) * 49;
                #pragma unroll
                for (int k = 0; k < 16; ++k) {
                    tr[k] += sc[k];
                    tf[k] += sc[16 + k];
                    tg[k] += sc[32 + k];
                }
            }
            const float* cb = ws + OFF_C + b * 256;
            int mi = mi0 + 4 * (tid >> 3), mj = mj0 + 4 * (tid & 7);
            float4 ce4 = *(const float4*)&cb[mj];
            float ce[4] = {ce4.x, ce4.y, ce4.z, ce4.w};
            float sum = 0.f;
            #pragma unroll
            for (int ii = 0; ii < 4; ++ii) {
                float ci = cb[mi + ii];
                float4 S4 = *(const float4*)&Smat[(mi + ii) * 256 + mj];
                float4 Q4 = *(const float4*)&Qmat[(mi + ii) * 256 + mj];
                float Sv[4] = {S4.x, S4.y, S4.z, S4.w};
                float Qv[4] = {Q4.x, Q4.y, Q4.z, Q4.w};
                #pragma unroll
                for (int kk = 0; kk < 4; ++kk)
                    sum += ci * ce[kk] * Sv[kk] * (Qv[kk] * tr[ii * 4 + kk] + tf[ii * 4 + kk] * tg[ii * 4 + kk]);
            }
            if (ti < tj) sum *= 2.f;
            #pragma unroll
            for (int off = 32; off > 0; off >>= 1)
                sum += __shfl_down(sum, off);
            if (tid == 0) {
                atomicAdd(&ws[OFF_SUM + b], sum);
                __threadfence();
                atomicAdd(&cnt[b], 1);   // release: epilogue b may finish
            }
        }
    } else {
        // ---- epilogue: pv/g1/g2/raw overlap producers; wait CNT==36 last ----
        int b = blk - 960;
        if (tid < 16) wait_flag2(flg + IFL_P + 2 * (16 * b + tid));
        __syncthreads();
        __threadfence();

        const float* ptb = ws + OFF_PT + b * 32768;
        const float* pnb = ws + OFF_PN + b * 32768;
        float* vs   = lds;          // [128]
        float* g1   = lds + 128;    // [256]
        float* g2   = lds + 384;    // [256]
        float* red  = lds + 640;    // [256]
        float* snrm = lds + 900;
        if (tid < 128) vs[tid] = state[(16 + b) * 128 + tid];
        __syncthreads();

        int m = tid;
        float pv = 0.f;
        #pragma unroll 8
        for (int j = 0; j < 128; ++j)
            pv += ptb[j * 256 + m] * vs[j];     // coalesced over m
        float cc  = ws[OFF_C  + b * 256 + m];
        float uvm = ws[OFF_UV + b * 256 + m];
        float avm = ws[OFF_AV + b * 256 + m];
        g1[m] = cc * pv  * uvm;
        g2[m] = cc * avm * uvm;
        __syncthreads();

        // raw_i = sum_mm W2[mm,i] g1[mm] + Pn[mm,i] g2[mm]; mm split 2 halves
        int i = tid & 127, half = tid >> 7;
        int mmlo = half * 128;
        float raw = 0.f;
        #pragma unroll 8
        for (int mm = mmlo; mm < mmlo + 128; ++mm)
            raw += W2[mm * 128 + i] * g1[mm] + pnb[mm * 128 + i] * g2[mm];
        red[tid] = raw;
        __syncthreads();

        if (tid == 0) {
            while (atomicAdd(&cnt[b], 0) < 36) __builtin_amdgcn_s_sleep(8);
            __threadfence();
            float tot = atomicAdd(&ws[OFF_SUM + b], 0.0f);  // coherent read
            snrm[0] = sqrtf(fmaxf(2.f * tot, 0.f));
        }
        __syncthreads();
        if (tid < 128) {
            float rawt = red[tid] + red[tid + 128];
            float vn = ws[OFF_VN + b];
            float a  = -0.5f * rawt / ((snrm[0] + 1e-6f) * (vn + 1e-6f));
            out[(16 + b) * 128 + tid] = a - 0.1f * state[b * 128 + tid];
        }
    }
}

extern "C" void kernel_launch(void* const* d_in, const int* in_sizes, int n_in,
                              void* d_out, int out_size, void* d_ws, size_t ws_size,
                              hipStream_t stream) {
    (void)in_sizes; (void)n_in; (void)out_size; (void)ws_size;
    const float* t     = (const float*)d_in[0];
    const float* state = (const float*)d_in[1];
    const float* x0    = (const float*)d_in[2];
    const float* x1    = (const float*)d_in[3];
    const float* W1    = (const float*)d_in[4];
    const float* b1    = (const float*)d_in[5];
    const float* W2    = (const float*)d_in[6];
    // b2 cancels in the Jacobian — unused.
    float* out = (float*)d_out;
    float* ws  = (float*)d_ws;

    k_all<<<976, 256, 0, stream>>>(t, state, x0, x1, W1, b1, W2, ws, out);
}

// Round 3
// 149.763 us; speedup vs baseline: 1.3807x; 1.3807x over previous
//
#include <hip/hip_runtime.h>
#include <math.h>

// Problem constants: N=128 features, H=256 hidden, B=16 batch.
//
// Analytic collapse of the reference:
//   S = W1^T W1  [256x256] (symmetric), Q = W2 W2^T [256x256] (symmetric)
//   per sample: d = 1-tanh^2(h), c = -2 z d,  P = S diag(d) W2  [256x128]
//   ||dG||_F^2 = 2 sum_{m,m'} c_m c_m' S[m,m'] ( Q[m,m'] R[m,m'] + M[m,m'] M[m',m] )
//        R = P P^T, M = P W2^T
//   Gamma contraction = 0.5*( W2^T (c .* Pv .* Uv) + P^T (c .* W2v .* Uv) )
//
// Session record (dur_us): R1 145.4 -> R2 126.9 -> R3 129.0 -> R4 218.5
// (grid.sync ~35us) -> R5 171.9 -> R6 124.3 -> R7 128.2 -> R8 115.0
// (3 kernels; fnorm 49KB all-resident + 16 single-lane spin epilogue blocks)
// -> R9 206.8 FAILED: one kernel, 3-deep flag chain, 64-lane polling ->
// atomic congestion collapse (kernel 162us, VALUBusy 4%, occupancy = the
// spinning waves; releases queued behind ~54K polling RMWs). Lesson: at most
// ONE spin level per kernel, SINGLE-LANE polling on per-b counters only.
// -> R10 (this): R8 structure, pmat3 merged into the fnorm kernel within the
// proven envelope: pmat blocks (no waits) release cnt2[b]; producers/epilogue
// poll cnt2[b]>=16 with tid0 only. Deadlock-free by capacity (37632B LDS ->
// 4 blk/CU -> 1024 slots >= 848) + topological block order. Bodies verbatim
// R8/R9 => bit-identical output expected.
// Lessons: (1) grid.sync ~35us - never. (2) low-occupancy streaming loops
// are latency-bound; LDS staging + 4-wave blocks win. (3) last-arrival
// epilogue fusion loses to dedicated overlap blocks. (4) harness fixed cost
// ~82us (268MB ws re-poison at ~80% HBM peak); kernel budget ~33us.

// ws layout (float offsets)
static constexpr int OFF_W2T  = 0;        // [128][256]
static constexpr int OFF_S    = 32768;    // [256][256]
static constexpr int OFF_Q    = 98304;    // [256][256]
static constexpr int OFF_D    = 163840;   // [16][256]
static constexpr int OFF_C    = 167936;   // [16][256]
static constexpr int OFF_UV   = 172032;   // [16][256]
static constexpr int OFF_AV   = 176128;   // [16][256]
static constexpr int OFF_VN   = 180224;   // [16]
static constexpr int OFF_SUM  = 180240;   // [16] float accumulator (fnorm^2/2)
static constexpr int OFF_CNT  = 180256;   // [16] int32: fnorm producers done
static constexpr int OFF_CNT2 = 180272;   // [16] int32: pmat blocks done
static constexpr int OFF_PT   = 180288;   // [16][128][256]  PT[b][j][m] = P[b][m][j]
static constexpr int OFF_PN   = OFF_PT + 16 * 32768;  // [16][256][128] row-major P
// total ~= 1.23M floats ~= 4.9 MB

// =====================================================================
// Stage 1 (176 blocks x 256 thr):
//   blocks   0..63 : S = W1^T W1
//   blocks  64..127: Q = W2 W2^T
//   blocks 128..159: W2T transpose
//   blocks 160..175: per-sample prep (+ zero SUM/CNT/CNT2, out rows 0..15)
// =====================================================================
__global__ __launch_bounds__(256) void k_stage1(const float* __restrict__ tptr,
                                                const float* __restrict__ state,
                                                const float* __restrict__ x0,
                                                const float* __restrict__ x1,
                                                const float* __restrict__ W1,
                                                const float* __restrict__ b1,
                                                const float* __restrict__ W2,
                                                float* __restrict__ ws,
                                                float* __restrict__ out) {
    __shared__ __align__(16) float smem[2 * 32 * 34];
    int blk = blockIdx.x;
    int tid = threadIdx.x;

    if (blk < 64) {
        // ---- S[m,n] = sum_k W1[k,m] W1[k,n], W1 is [128][256] ----
        float* Ai = smem;            // [32][34] : [k][m]
        float* Aj = smem + 1088;
        int m0 = (blk >> 3) * 32, n0 = (blk & 7) * 32;
        int lx = tid & 31, lr = tid >> 5;
        int tx = tid & 15, ty = tid >> 4;
        float a00 = 0, a01 = 0, a10 = 0, a11 = 0;
        for (int kc = 0; kc < 128; kc += 32) {
            #pragma unroll
            for (int i = 0; i < 4; ++i) {
                int k = lr + 8 * i;
                Ai[k * 34 + lx] = W1[(kc + k) * 256 + m0 + lx];
                Aj[k * 34 + lx] = W1[(kc + k) * 256 + n0 + lx];
            }
            __syncthreads();
            #pragma unroll
            for (int k = 0; k < 32; ++k) {
                float2 a = *(const float2*)&Ai[k * 34 + 2 * ty];
                float2 b = *(const float2*)&Aj[k * 34 + 2 * tx];
                a00 += a.x * b.x; a01 += a.x * b.y;
                a10 += a.y * b.x; a11 += a.y * b.y;
            }
            __syncthreads();
        }
        float* S = ws + OFF_S;
        int m = m0 + 2 * ty, n = n0 + 2 * tx;
        S[m * 256 + n]           = a00;
        S[m * 256 + n + 1]       = a01;
        S[(m + 1) * 256 + n]     = a10;
        S[(m + 1) * 256 + n + 1] = a11;
    } else if (blk < 128) {
        // ---- Q[m,n] = sum_j W2[m,j] W2[n,j], W2 is [256][128] ----
        float* Xi = smem;            // [32][34] : [j][m]
        float* Xj = smem + 1088;
        int bq = blk - 64;
        int m0 = (bq >> 3) * 32, n0 = (bq & 7) * 32;
        int lx = tid & 31, lr = tid >> 5;
        int tx = tid & 15, ty = tid >> 4;
        float a00 = 0, a01 = 0, a10 = 0, a11 = 0;
        for (int kc = 0; kc < 128; kc += 32) {
            #pragma unroll
            for (int i = 0; i < 4; ++i) {
                Xi[lx * 34 + lr + 8 * i] = W2[(m0 + lr + 8 * i) * 128 + kc + lx];
                Xj[lx * 34 + lr + 8 * i] = W2[(n0 + lr + 8 * i) * 128 + kc + lx];
            }
            __syncthreads();
            #pragma unroll
            for (int k = 0; k < 32; ++k) {
                float2 a = *(const float2*)&Xi[k * 34 + 2 * ty];
                float2 b = *(const float2*)&Xj[k * 34 + 2 * tx];
                a00 += a.x * b.x; a01 += a.x * b.y;
                a10 += a.y * b.x; a11 += a.y * b.y;
            }
            __syncthreads();
        }
        float* Q = ws + OFF_Q;
        int m = m0 + 2 * ty, n = n0 + 2 * tx;
        Q[m * 256 + n]           = a00;
        Q[m * 256 + n + 1]       = a01;
        Q[(m + 1) * 256 + n]     = a10;
        Q[(m + 1) * 256 + n + 1] = a11;
    } else if (blk < 160) {
        // ---- W2T[c][r] = W2[r][c] ----
        float* tile = smem;  // [32][33]
        int b2 = blk - 128;
        int c0 = (b2 & 3) * 32, r0 = (b2 >> 2) * 32;
        int tx = tid & 31, ty = tid >> 5;
        #pragma unroll
        for (int i = 0; i < 32; i += 8)
            tile[(ty + i) * 33 + tx] = W2[(r0 + ty + i) * 128 + c0 + tx];
        __syncthreads();
        float* W2T = ws + OFF_W2T;
        #pragma unroll
        for (int i = 0; i < 32; i += 8)
            W2T[(c0 + ty + i) * 256 + r0 + tx] = tile[tx * 33 + ty + i];
    } else {
        // ---- per-sample prep ----
        int b = blk - 160;
        float* xs  = smem;
        float* vs  = smem + 128;
        float* red = smem + 256;
        float t = tptr[0];
        float w = 4.f * t * (1.f - t);
        if (tid == 0) {
            ws[OFF_SUM + b] = 0.f;
            ((int*)ws)[OFF_CNT + b]  = 0;
            ((int*)ws)[OFF_CNT2 + b] = 0;
        }
        if (tid < 128) {
            float dev = state[b * 128 + tid];
            float v   = state[(16 + b) * 128 + tid];
            float xv  = x0[b * 128 + tid] + t * (x1[b * 128 + tid] - x0[b * 128 + tid]) + w * dev;
            xs[tid] = xv;
            vs[tid] = v;
            out[b * 128 + tid] = v;   // first-half output = dev_velocity
            red[tid] = v * v;
        }
        __syncthreads();
        for (int s = 64; s > 0; s >>= 1) {
            if (tid < s) red[tid] += red[tid + s];
            __syncthreads();
        }
        if (tid == 0) ws[OFF_VN + b] = sqrtf(red[0]);

        int m = tid;  // 0..255
        float h = b1[m], uvm = 0.f;
        #pragma unroll 8
        for (int k = 0; k < 128; ++k) {
            float wv = W1[k * 256 + m];    // coalesced
            h   += xs[k] * wv;
            uvm += vs[k] * wv;
        }
        float z  = tanhf(h);
        float dd = 1.f - z * z;
        float cc = -2.f * z * dd;
        const float4* w2r = (const float4*)&W2[m * 128];
        const float4* vs4 = (const float4*)vs;
        float avm = 0.f;
        #pragma unroll 8
        for (int j4 = 0; j4 < 32; ++j4) {
            float4 ww = w2r[j4];
            float4 vv = vs4[j4];
            avm += ww.x * vv.x + ww.y * vv.y + ww.z * vv.z + ww.w * vv.w;
        }
        ws[OFF_D  + b * 256 + m] = dd;
        ws[OFF_C  + b * 256 + m] = cc;
        ws[OFF_UV + b * 256 + m] = uvm;
        ws[OFF_AV + b * 256 + m] = avm;
    }
}

// =====================================================================
// Fused pmat + fnorm + epilogue. Grid 848 x 256 thr, all-resident
// (LDS 37632B -> 4 blocks/CU, launch_bounds(256,4) => 1024 slots >= 848).
// ONE spin level, single-lane polling on per-b counters:
//   blk   0..255: pmat (no waits; S/D from kernel1); release cnt2[b]
//   blk 256..831: fnorm producers: tid0 polls cnt2[b]>=16; release cnt[b]
//   blk 832..847: epilogue: tid0 polls cnt2[b]>=16 (pv/raw work overlaps
//                 producers), then cnt[b]>=36 for the final snrm scaling
// =====================================================================
__global__ __launch_bounds__(256, 4) void k_pfuse(const float* __restrict__ state,
                                                  const float* __restrict__ W2,
                                                  float* __restrict__ ws,
                                                  float* __restrict__ out) {
    __shared__ __align__(16) float lds[9408];   // 37632 B
    int blk = blockIdx.x;
    int tid = threadIdx.x;
    int* cnt  = (int*)ws + OFF_CNT;
    int* cnt2 = (int*)ws + OFF_CNT2;

    if (blk < 256) {
        // ---- pmat: P = S diag(d) W2, 32m x 64j tile, 4x2/thread ----
        int q = blk;
        int b = q >> 4, rem = q & 15;
        int mt = rem >> 1, jt = rem & 1;
        float* ST = lds;             // [32][36] : [n][m-local]
        float* YT = lds + 1152;      // [32][68] : [n][j-local]
        const float* Smat = ws + OFF_S;
        const float* dvec = ws + OFF_D + b * 256;
        int m0 = mt * 32, j0 = jt * 64;
        int n = tid >> 3, c4 = (tid & 7) * 4;    // staging
        int ty = tid >> 5, tx = tid & 31;        // compute: 4m x 2j
        float acc[4][2] = {};
        for (int nc = 0; nc < 256; nc += 32) {
            // S symmetric: S[m,n] = S[n,m] -> coalesced row reads
            *(float4*)&ST[n * 36 + c4] = *(const float4*)&Smat[(nc + n) * 256 + m0 + c4];
            float dn = dvec[nc + n];
            #pragma unroll
            for (int i = 0; i < 2; ++i) {
                int col = c4 + 32 * i;
                float4 wv = *(const float4*)&W2[(nc + n) * 128 + j0 + col];
                wv.x *= dn; wv.y *= dn; wv.z *= dn; wv.w *= dn;
                *(float4*)&YT[n * 68 + col] = wv;
            }
            __syncthreads();
            #pragma unroll 8
            for (int k = 0; k < 32; ++k) {
                float4 a  = *(const float4*)&ST[k * 36 + 4 * ty];
                float2 bb = *(const float2*)&YT[k * 68 + 2 * tx];
                acc[0][0] += a.x * bb.x; acc[0][1] += a.x * bb.y;
                acc[1][0] += a.y * bb.x; acc[1][1] += a.y * bb.y;
                acc[2][0] += a.z * bb.x; acc[2][1] += a.z * bb.y;
                acc[3][0] += a.w * bb.x; acc[3][1] += a.w * bb.y;
            }
            __syncthreads();
        }
        float* ptb = ws + OFF_PT + b * 32768;
        float* pnb = ws + OFF_PN + b * 32768;
        #pragma unroll
        for (int jj = 0; jj < 2; ++jj) {
            float4 v = make_float4(acc[0][jj], acc[1][jj], acc[2][jj], acc[3][jj]);
            *(float4*)&ptb[(j0 + 2 * tx + jj) * 256 + m0 + 4 * ty] = v;
        }
        #pragma unroll
        for (int ii = 0; ii < 4; ++ii) {
            float2 v = make_float2(acc[ii][0], acc[ii][1]);
            *(float2*)&pnb[(m0 + 4 * ty + ii) * 128 + j0 + 2 * tx] = v;
        }
        __syncthreads();
        if (tid == 0) { __threadfence(); atomicAdd(&cnt2[b], 1); }
    } else if (blk < 832) {
        // ---- fnorm producer: triangular (mi,mj) tile, 4 waves x j-quarter ----
        int q = blk - 256;
        int idx = q >> 4;          // 0..35 triangular tile
        int b   = q & 15;
        if (tid == 0) {
            while (atomicAdd(&cnt2[b], 0) < 16) __builtin_amdgcn_s_sleep(4);
            __threadfence();
        }
        __syncthreads();

        int tj = 0;
        while ((tj + 1) * (tj + 2) / 2 <= idx) ++tj;
        int ti = idx - tj * (tj + 1) / 2;      // ti <= tj
        int mi0 = ti * 32, mj0 = tj * 32;
        float* PiT = lds;              // [64][32] per round
        float* PjT = lds + 2048;
        float* WiT = lds + 4096;
        float* WjT = lds + 6144;
        const float* ptb  = ws + OFF_PT + b * 32768;
        const float* W2T  = ws + OFF_W2T;
        const float* Smat = ws + OFF_S;
        const float* Qmat = ws + OFF_Q;
        int jr = tid >> 3, jc4 = (tid & 7) * 4;
        int w = tid >> 6, s = tid & 63;
        int ty = s >> 3, tx = s & 7;
        float r[4][4] = {}, f[4][4] = {}, g[4][4] = {};
        // Two staging rounds; round rr stages global j = 32*(l>>4)+16*rr+(l&15)
        // for local row l in [0,64): wave w's rows [16w,16w+16) are global
        // j in [32w+16rr, +16) -> same per-wave j set & order as R8.
        #pragma unroll
        for (int rr = 0; rr < 2; ++rr) {
            #pragma unroll
            for (int it = 0; it < 2; ++it) {
                int l = jr + 32 * it;
                int j = 32 * (l >> 4) + 16 * rr + (l & 15);
                *(float4*)&PiT[l * 32 + jc4] = *(const float4*)&ptb[j * 256 + mi0 + jc4];
                *(float4*)&PjT[l * 32 + jc4] = *(const float4*)&ptb[j * 256 + mj0 + jc4];
                *(float4*)&WiT[l * 32 + jc4] = *(const float4*)&W2T[j * 256 + mi0 + jc4];
                *(float4*)&WjT[l * 32 + jc4] = *(const float4*)&W2T[j * 256 + mj0 + jc4];
            }
            __syncthreads();
            #pragma unroll 4
            for (int jj = 0; jj < 16; ++jj) {
                int l = 16 * w + jj;
                float4 pi4 = *(const float4*)&PiT[l * 32 + 4 * ty];
                float4 pj4 = *(const float4*)&PjT[l * 32 + 4 * tx];
                float4 wi4 = *(const float4*)&WiT[l * 32 + 4 * ty];
                float4 wj4 = *(const float4*)&WjT[l * 32 + 4 * tx];
                float pi[4] = {pi4.x, pi4.y, pi4.z, pi4.w};
                float pj[4] = {pj4.x, pj4.y, pj4.z, pj4.w};
                float wi[4] = {wi4.x, wi4.y, wi4.z, wi4.w};
                float wj[4] = {wj4.x, wj4.y, wj4.z, wj4.w};
                #pragma unroll
                for (int ii = 0; ii < 4; ++ii)
                    #pragma unroll
                    for (int kk = 0; kk < 4; ++kk) {
                        r[ii][kk] += pi[ii] * pj[kk];   // R[mi,mj]
                        f[ii][kk] += pi[ii] * wj[kk];   // M[mi,mj]
                        g[ii][kk] += pj[kk] * wi[ii];   // M[mj,mi]
                    }
            }
            __syncthreads();   // round rr done; safe to restage
        }
        // 3-wave scratch: waves 1..3 spill; wave 0 keeps registers.
        if (w != 0) {
            float* scr = lds;
            int base = ((w - 1) * 64 + s) * 49;   // stride 49: conflict-light
            #pragma unroll
            for (int ii = 0; ii < 4; ++ii)
                #pragma unroll
                for (int kk = 0; kk < 4; ++kk) {
                    scr[base + ii * 4 + kk]      = r[ii][kk];
                    scr[base + 16 + ii * 4 + kk] = f[ii][kk];
                    scr[base + 32 + ii * 4 + kk] = g[ii][kk];
                }
        }
        __syncthreads();
        if (tid < 64) {
            float tr[16], tf[16], tg[16];
            #pragma unroll
            for (int ii = 0; ii < 4; ++ii)
                #pragma unroll
                for (int kk = 0; kk < 4; ++kk) {
                    tr[ii * 4 + kk] = r[ii][kk];
                    tf[ii * 4 + kk] = f[ii][kk];
                    tg[ii * 4 + kk] = g[ii][kk];
                }
            // add waves 1..3 in order -> same w0+w1+w2+w3 order as R8
            for (int ww = 0; ww < 3; ++ww) {
                const float* sc = lds + (ww * 64 + tid) * 49;
                #pragma unroll
                for (int k = 0; k < 16; ++k) {
                    tr[k] += sc[k];
                    tf[k] += sc[16 + k];
                    tg[k] += sc[32 + k];
                }
            }
            const float* cb = ws + OFF_C + b * 256;
            int mi = mi0 + 4 * (tid >> 3), mj = mj0 + 4 * (tid & 7);
            float4 ce4 = *(const float4*)&cb[mj];
            float ce[4] = {ce4.x, ce4.y, ce4.z, ce4.w};
            float sum = 0.f;
            #pragma unroll
            for (int ii = 0; ii < 4; ++ii) {
                float ci = cb[mi + ii];
                float4 S4 = *(const float4*)&Smat[(mi + ii) * 256 + mj];
                float4 Q4 = *(const float4*)&Qmat[(mi + ii) * 256 + mj];
                float Sv[4] = {S4.x, S4.y, S4.z, S4.w};
                float Qv[4] = {Q4.x, Q4.y, Q4.z, Q4.w};
                #pragma unroll
                for (int kk = 0; kk < 4; ++kk)
                    sum += ci * ce[kk] * Sv[kk] * (Qv[kk] * tr[ii * 4 + kk] + tf[ii * 4 + kk] * tg[ii * 4 + kk]);
            }
            if (ti < tj) sum *= 2.f;
            #pragma unroll
            for (int off = 32; off > 0; off >>= 1)
                sum += __shfl_down(sum, off);
            if (tid == 0) {
                atomicAdd(&ws[OFF_SUM + b], sum);
                __threadfence();
                atomicAdd(&cnt[b], 1);   // release: epilogue b may finish
            }
        }
    } else {
        // ---- epilogue: pv/g1/g2/raw overlap producers; wait CNT==36 last ----
        int b = blk - 832;
        if (tid == 0) {
            while (atomicAdd(&cnt2[b], 0) < 16) __builtin_amdgcn_s_sleep(4);
            __threadfence();
        }
        __syncthreads();

        const float* ptb = ws + OFF_PT + b * 32768;
        const float* pnb = ws + OFF_PN + b * 32768;
        float* vs   = lds;          // [128]
        float* g1   = lds + 128;    // [256]
        float* g2   = lds + 384;    // [256]
        float* red  = lds + 640;    // [256]
        float* snrm = lds + 900;
        if (tid < 128) vs[tid] = state[(16 + b) * 128 + tid];
        __syncthreads();

        int m = tid;
        float pv = 0.f;
        #pragma unroll 8
        for (int j = 0; j < 128; ++j)
            pv += ptb[j * 256 + m] * vs[j];     // coalesced over m
        float cc  = ws[OFF_C  + b * 256 + m];
        float uvm = ws[OFF_UV + b * 256 + m];
        float avm = ws[OFF_AV + b * 256 + m];
        g1[m] = cc * pv  * uvm;
        g2[m] = cc * avm * uvm;
        __syncthreads();

        // raw_i = sum_mm W2[mm,i] g1[mm] + Pn[mm,i] g2[mm]; mm split 2 halves
        int i = tid & 127, half = tid >> 7;
        int mmlo = half * 128;
        float raw = 0.f;
        #pragma unroll 8
        for (int mm = mmlo; mm < mmlo + 128; ++mm)
            raw += W2[mm * 128 + i] * g1[mm] + pnb[mm * 128 + i] * g2[mm];
        red[tid] = raw;
        __syncthreads();

        if (tid == 0) {
            while (atomicAdd(&cnt[b], 0) < 36) __builtin_amdgcn_s_sleep(4);
            __threadfence();
            float tot = atomicAdd(&ws[OFF_SUM + b], 0.0f);  // coherent read
            snrm[0] = sqrtf(fmaxf(2.f * tot, 0.f));
        }
        __syncthreads();
        if (tid < 128) {
            float rawt = red[tid] + red[tid + 128];
            float vn = ws[OFF_VN + b];
            float a  = -0.5f * rawt / ((snrm[0] + 1e-6f) * (vn + 1e-6f));
            out[(16 + b) * 128 + tid] = a - 0.1f * state[b * 128 + tid];
        }
    }
}

extern "C" void kernel_launch(void* const* d_in, const int* in_sizes, int n_in,
                              void* d_out, int out_size, void* d_ws, size_t ws_size,
                              hipStream_t stream) {
    (void)in_sizes; (void)n_in; (void)out_size; (void)ws_size;
    const float* t     = (const float*)d_in[0];
    const float* state = (const float*)d_in[1];
    const float* x0    = (const float*)d_in[2];
    const float* x1    = (const float*)d_in[3];
    const float* W1    = (const float*)d_in[4];
    const float* b1    = (const float*)d_in[5];
    const float* W2    = (const float*)d_in[6];
    // b2 cancels in the Jacobian — unused.
    float* out = (float*)d_out;
    float* ws  = (float*)d_ws;

    k_stage1<<<176, 256, 0, stream>>>(t, state, x0, x1, W1, b1, W2, ws, out);
    k_pfuse<<<848, 256, 0, stream>>>(state, W2, ws, out);
}